// Round 5
// baseline (64.486 us; speedup 1.0000x reference)
//
#include <hip/hip_runtime.h>

// Problem constants
#define B_ 4
#define T_ 1024
#define D_ 1024
#define H_ 2048
#define E_ 8
#define N_ (B_ * T_)

// --------------------------------------------------------------------------
// Kernel A: w2sum[r] = sum_d w2_flat[r, d], r in [0, E*H), row = D contiguous.
// 1024 blocks x 256 thr = 4096 waves; each wave reduces 4 consecutive rows.
// (256,1): allow high VGPR so all 16 float4 loads stay in flight.
// --------------------------------------------------------------------------
__global__ __launch_bounds__(256, 1) void w2sum_kernel(const float* __restrict__ w2,
                                                       float* __restrict__ w2sum) {
    int wave = (blockIdx.x * 256 + threadIdx.x) >> 6;   // 0..4095
    int lane = threadIdx.x & 63;
    const float4* p = (const float4*)(w2 + (size_t)wave * 4 * D_) + lane;

    float4 a00 = p[0],        a01 = p[64],       a02 = p[128],       a03 = p[192];
    float4 a10 = p[256 + 0],  a11 = p[256 + 64], a12 = p[256 + 128], a13 = p[256 + 192];
    float4 a20 = p[512 + 0],  a21 = p[512 + 64], a22 = p[512 + 128], a23 = p[512 + 192];
    float4 a30 = p[768 + 0],  a31 = p[768 + 64], a32 = p[768 + 128], a33 = p[768 + 192];

    float acc0 = (a00.x+a00.y+a00.z+a00.w)+(a01.x+a01.y+a01.z+a01.w)
               + (a02.x+a02.y+a02.z+a02.w)+(a03.x+a03.y+a03.z+a03.w);
    float acc1 = (a10.x+a10.y+a10.z+a10.w)+(a11.x+a11.y+a11.z+a11.w)
               + (a12.x+a12.y+a12.z+a12.w)+(a13.x+a13.y+a13.z+a13.w);
    float acc2 = (a20.x+a20.y+a20.z+a20.w)+(a21.x+a21.y+a21.z+a21.w)
               + (a22.x+a22.y+a22.z+a22.w)+(a23.x+a23.y+a23.z+a23.w);
    float acc3 = (a30.x+a30.y+a30.z+a30.w)+(a31.x+a31.y+a31.z+a31.w)
               + (a32.x+a32.y+a32.z+a32.w)+(a33.x+a33.y+a33.z+a33.w);

#pragma unroll
    for (int off = 32; off >= 1; off >>= 1) {
        acc0 += __shfl_xor(acc0, off, 64);
        acc1 += __shfl_xor(acc1, off, 64);
        acc2 += __shfl_xor(acc2, off, 64);
        acc3 += __shfl_xor(acc3, off, 64);
    }
    if (lane == 0) {
        float* o = w2sum + wave * 4;
        o[0] = acc0; o[1] = acc1; o[2] = acc2; o[3] = acc3;
    }
}

// --------------------------------------------------------------------------
// Kernel B: vT[d*E + e] = dot(w1[e,d,:], w2sum[e,:]).
// Block = 1 expert x 8 rows (1024 blocks, 256 thr); wave = 2 rows.
// w2sum[e] staged in LDS once per block -> the FMA chain depends only on
// 16 INDEPENDENT global float4 loads of w1 per wave. (256,1) keeps them
// all in flight. c[e] computed from LDS by wave 0 of each expert's first
// block.
// --------------------------------------------------------------------------
__global__ __launch_bounds__(256, 1) void v_build_kernel(const float* __restrict__ w1,
                                                         const float* __restrict__ w2sum,
                                                         const float* __restrict__ b1,
                                                         const float* __restrict__ b2,
                                                         float* __restrict__ vT,
                                                         float* __restrict__ c) {
    int bid  = blockIdx.x;             // 0..1023
    int e    = bid >> 7;               // 128 blocks per expert
    int d0   = (bid & 127) * 8;        // first row (d) of this block
    int wid  = threadIdx.x >> 6;       // 0..3
    int lane = threadIdx.x & 63;

    __shared__ float sm[H_];           // 8 KB: w2sum[e,:]
    {
        const float4* g = (const float4*)(w2sum + (size_t)e * H_);
        float4* l = (float4*)sm;
        l[threadIdx.x]       = g[threadIdx.x];        // 512 float4 total
        l[threadIdx.x + 256] = g[threadIdx.x + 256];
    }
    __syncthreads();

    int dA = d0 + wid * 2;             // this wave's first row
    const float4* a = (const float4*)(w1 + ((size_t)e * D_ + dA) * H_) + lane;
    float4 a0 = a[0],   a1 = a[64],  a2 = a[128], a3 = a[192],
           a4 = a[256], a5 = a[320], a6 = a[384], a7 = a[448];
    const float4* b = a + (H_ / 4);    // next row
    float4 c0 = b[0],   c1 = b[64],  c2 = b[128], c3 = b[192],
           c4 = b[256], c5 = b[320], c6 = b[384], c7 = b[448];

    const float4* sp = (const float4*)sm + lane;
    float4 s0 = sp[0],   s1 = sp[64],  s2 = sp[128], s3 = sp[192],
           s4 = sp[256], s5 = sp[320], s6 = sp[384], s7 = sp[448];

    float acc0 = a0.x*s0.x + a0.y*s0.y + a0.z*s0.z + a0.w*s0.w
               + a1.x*s1.x + a1.y*s1.y + a1.z*s1.z + a1.w*s1.w
               + a2.x*s2.x + a2.y*s2.y + a2.z*s2.z + a2.w*s2.w
               + a3.x*s3.x + a3.y*s3.y + a3.z*s3.z + a3.w*s3.w
               + a4.x*s4.x + a4.y*s4.y + a4.z*s4.z + a4.w*s4.w
               + a5.x*s5.x + a5.y*s5.y + a5.z*s5.z + a5.w*s5.w
               + a6.x*s6.x + a6.y*s6.y + a6.z*s6.z + a6.w*s6.w
               + a7.x*s7.x + a7.y*s7.y + a7.z*s7.z + a7.w*s7.w;
    float acc1 = c0.x*s0.x + c0.y*s0.y + c0.z*s0.z + c0.w*s0.w
               + c1.x*s1.x + c1.y*s1.y + c1.z*s1.z + c1.w*s1.w
               + c2.x*s2.x + c2.y*s2.y + c2.z*s2.z + c2.w*s2.w
               + c3.x*s3.x + c3.y*s3.y + c3.z*s3.z + c3.w*s3.w
               + c4.x*s4.x + c4.y*s4.y + c4.z*s4.z + c4.w*s4.w
               + c5.x*s5.x + c5.y*s5.y + c5.z*s5.z + c5.w*s5.w
               + c6.x*s6.x + c6.y*s6.y + c6.z*s6.z + c6.w*s6.w
               + c7.x*s7.x + c7.y*s7.y + c7.z*s7.z + c7.w*s7.w;

#pragma unroll
    for (int off = 32; off >= 1; off >>= 1) {
        acc0 += __shfl_xor(acc0, off, 64);
        acc1 += __shfl_xor(acc1, off, 64);
    }
    if (lane == 0) {
        vT[(size_t)dA * E_ + e]       = acc0;
        vT[(size_t)(dA + 1) * E_ + e] = acc1;
    }

    // c[e] = dot(b1[e,:], w2sum[e,:]) + sum_d b2[e,d]
    // First block of each expert, wave 0; w2sum read from LDS.
    if ((bid & 127) == 0 && wid == 0) {
        float s = 0.f;
        for (int k = lane; k < H_; k += 64) s += b1[(size_t)e * H_ + k] * sm[k];
        for (int k = lane; k < D_; k += 64) s += b2[(size_t)e * D_ + k];
#pragma unroll
        for (int off = 32; off >= 1; off >>= 1) s += __shfl_xor(s, off, 64);
        if (lane == 0) c[e] = s;
    }
}

// --------------------------------------------------------------------------
// Kernel C: per-token gating + collapsed expert sum. 2 tokens per wave.
//   logits[e] = x[n,:].wg[:,e] ; dv[e] = x[n,:].vT[:,e]
//   top-2 (tie -> lower index); g1 = 1/(1+exp(l0-l1)); s[n] = sum g*(dv+c)
// 512 blocks x 256 thr = 2048 waves.
// --------------------------------------------------------------------------
__global__ __launch_bounds__(256) void token_kernel(const float* __restrict__ x,
                                                    const float* __restrict__ wg,
                                                    const float* __restrict__ vT,
                                                    const float* __restrict__ c,
                                                    float* __restrict__ s) {
    int w = (blockIdx.x * 256 + threadIdx.x) >> 6;      // 0..2047
    int lane = threadIdx.x & 63;
    int n0 = w * 2;
    const float* x0 = x + (size_t)n0 * D_;
    const float* x1 = x0 + D_;

    float lgA[E_] = {0.f,0.f,0.f,0.f,0.f,0.f,0.f,0.f};
    float dvA[E_] = {0.f,0.f,0.f,0.f,0.f,0.f,0.f,0.f};
    float lgB[E_] = {0.f,0.f,0.f,0.f,0.f,0.f,0.f,0.f};
    float dvB[E_] = {0.f,0.f,0.f,0.f,0.f,0.f,0.f,0.f};

#pragma unroll
    for (int k = 0; k < D_ / 64; ++k) {                 // 16 iters
        int d = lane + 64 * k;
        float xa = x0[d];
        float xb = x1[d];
        const float4* wgp = (const float4*)(wg + (size_t)d * E_);
        const float4* vp  = (const float4*)(vT + (size_t)d * E_);
        float4 g0 = wgp[0], g1 = wgp[1];
        float4 v0 = vp[0],  v1 = vp[1];
        lgA[0] += xa * g0.x; lgA[1] += xa * g0.y; lgA[2] += xa * g0.z; lgA[3] += xa * g0.w;
        lgA[4] += xa * g1.x; lgA[5] += xa * g1.y; lgA[6] += xa * g1.z; lgA[7] += xa * g1.w;
        dvA[0] += xa * v0.x; dvA[1] += xa * v0.y; dvA[2] += xa * v0.z; dvA[3] += xa * v0.w;
        dvA[4] += xa * v1.x; dvA[5] += xa * v1.y; dvA[6] += xa * v1.z; dvA[7] += xa * v1.w;
        lgB[0] += xb * g0.x; lgB[1] += xb * g0.y; lgB[2] += xb * g0.z; lgB[3] += xb * g0.w;
        lgB[4] += xb * g1.x; lgB[5] += xb * g1.y; lgB[6] += xb * g1.z; lgB[7] += xb * g1.w;
        dvB[0] += xb * v0.x; dvB[1] += xb * v0.y; dvB[2] += xb * v0.z; dvB[3] += xb * v0.w;
        dvB[4] += xb * v1.x; dvB[5] += xb * v1.y; dvB[6] += xb * v1.z; dvB[7] += xb * v1.w;
    }

#pragma unroll
    for (int off = 32; off >= 1; off >>= 1) {
#pragma unroll
        for (int e = 0; e < E_; ++e) {
            lgA[e] += __shfl_xor(lgA[e], off, 64);
            dvA[e] += __shfl_xor(dvA[e], off, 64);
            lgB[e] += __shfl_xor(lgB[e], off, 64);
            dvB[e] += __shfl_xor(dvB[e], off, 64);
        }
    }

    if (lane == 0 || lane == 32) {
        const float* lg = (lane == 0) ? lgA : lgB;
        const float* dv = (lane == 0) ? dvA : dvB;
        int n = (lane == 0) ? n0 : (n0 + 1);
        int e0 = 0;
#pragma unroll
        for (int e = 1; e < E_; ++e) if (lg[e] > lg[e0]) e0 = e;
        int e1 = (e0 == 0) ? 1 : 0;
#pragma unroll
        for (int e = 0; e < E_; ++e) {
            if (e == e0) continue;
            if (lg[e] > lg[e1]) e1 = e;
        }
        float l0 = lg[e0], l1 = lg[e1];
        float g1w = 1.f / (1.f + expf(l0 - l1));
        float g0w = 1.f - g1w;
        s[n] = g0w * (dv[e0] + c[e0]) + g1w * (dv[e1] + c[e1]);
    }
}

// --------------------------------------------------------------------------
// Kernel D: out[b, t] = s[b, t] - logsumexp_t(s[b, :]).
// One block, 4 waves, wave per batch row; 16 values per lane.
// --------------------------------------------------------------------------
__global__ __launch_bounds__(256) void lsm_kernel(const float* __restrict__ s,
                                                  float* __restrict__ out) {
    int brow = threadIdx.x >> 6;                        // 0..3
    int lane = threadIdx.x & 63;
    const float* row = s + (size_t)brow * T_;
    float vals[16];
    float mx = -3.0e38f;
#pragma unroll
    for (int k = 0; k < 16; ++k) {
        vals[k] = row[lane + 64 * k];
        mx = fmaxf(mx, vals[k]);
    }
#pragma unroll
    for (int off = 32; off >= 1; off >>= 1) mx = fmaxf(mx, __shfl_xor(mx, off, 64));
    float sm = 0.f;
#pragma unroll
    for (int k = 0; k < 16; ++k) sm += expf(vals[k] - mx);
#pragma unroll
    for (int off = 32; off >= 1; off >>= 1) sm += __shfl_xor(sm, off, 64);
    float lse = mx + logf(sm);
#pragma unroll
    for (int k = 0; k < 16; ++k) out[(size_t)brow * T_ + lane + 64 * k] = vals[k] - lse;
}

// --------------------------------------------------------------------------
extern "C" void kernel_launch(void* const* d_in, const int* in_sizes, int n_in,
                              void* d_out, int out_size, void* d_ws, size_t ws_size,
                              hipStream_t stream) {
    const float* x  = (const float*)d_in[0];   // [B, T, D]
    const float* wg = (const float*)d_in[1];   // [D, E]
    const float* w1 = (const float*)d_in[2];   // [E, D, H]
    const float* b1 = (const float*)d_in[3];   // [E, H]
    const float* w2 = (const float*)d_in[4];   // [E, H, D]
    const float* b2 = (const float*)d_in[5];   // [E, D]
    float* out = (float*)d_out;                // [B, T]

    float* ws     = (float*)d_ws;
    float* w2sum  = ws;                 // E*H = 16384 floats
    float* vT     = ws + 16384;         // D*E =  8192 floats (transposed: [D][E])
    float* c      = ws + 24576;         // E   =     8 floats
    float* s      = ws + 24592;         // N   =  4096 floats

    // A: 16384 rows, 4/wave -> 4096 waves -> 1024 blocks
    w2sum_kernel<<<dim3(1024), dim3(256), 0, stream>>>(w2, w2sum);
    // B: 1024 blocks (expert x 8-row group); wave = 2 rows; LDS-staged w2sum
    v_build_kernel<<<dim3(1024), dim3(256), 0, stream>>>(w1, w2sum, b1, b2, vT, c);
    // C: 4096 tokens, 2/wave -> 2048 waves -> 512 blocks
    token_kernel<<<dim3(512), dim3(256), 0, stream>>>(x, wg, vT, c, s);
    // D: log-softmax over T per batch row, single block
    lsm_kernel<<<dim3(1), dim3(256), 0, stream>>>(s, out);
}

// Round 6
// 49.560 us; speedup vs baseline: 1.3012x; 1.3012x over previous
//
#include <hip/hip_runtime.h>
#include <stdint.h>

// Problem constants
#define B_ 4
#define T_ 1024
#define D_ 1024
#define H_ 2048
#define E_ 8
#define N_ (B_ * T_)

// Fire-and-forget global->LDS staging, 16B per lane per issue.
// LDS dest is wave-uniform base + lane*16 (pass the same l for all lanes);
// global src is per-lane.
__device__ __forceinline__ void stage16(const float* g, float* l) {
    __builtin_amdgcn_global_load_lds(
        (const __attribute__((address_space(1))) uint32_t*)g,
        (__attribute__((address_space(3))) uint32_t*)l,
        16, 0, 0);
}

// --------------------------------------------------------------------------
// Kernel A: w2sum[r] = sum_d w2_flat[r, d], row = D = 1024 contiguous floats.
// 2048 blocks x 256 thr. Block stages 8 rows (32 KB) into LDS via
// global_load_lds (8 independent issues per thread, no data VGPRs), then
// wave w reduces local rows 2w, 2w+1 from LDS.
// --------------------------------------------------------------------------
__global__ __launch_bounds__(256) void w2sum_kernel(const float* __restrict__ w2,
                                                    float* __restrict__ w2sum) {
    __shared__ float sm[8 * D_];                       // 32 KB
    int wid  = threadIdx.x >> 6;
    int lane = threadIdx.x & 63;
    const float* src = w2 + (size_t)blockIdx.x * 8 * D_;

#pragma unroll
    for (int i = 0; i < 8; ++i) {
        int base = i * 1024 + wid * 256;               // float idx, wave-uniform
        stage16(src + base + lane * 4, sm + base);
    }
    asm volatile("s_waitcnt vmcnt(0)" ::: "memory");
    __syncthreads();

    // wave w: local rows 2w, 2w+1 (1024 floats each)
    float acc0 = 0.f, acc1 = 0.f;
    const float* r0 = sm + (wid * 2) * D_;
    const float* r1 = r0 + D_;
#pragma unroll
    for (int k = 0; k < 4; ++k) {
        float4 a = *(const float4*)&r0[lane * 4 + k * 256];
        float4 b = *(const float4*)&r1[lane * 4 + k * 256];
        acc0 += a.x + a.y + a.z + a.w;
        acc1 += b.x + b.y + b.z + b.w;
    }
#pragma unroll
    for (int off = 32; off >= 1; off >>= 1) {
        acc0 += __shfl_xor(acc0, off, 64);
        acc1 += __shfl_xor(acc1, off, 64);
    }
    if (lane == 0) {
        int r = blockIdx.x * 8 + wid * 2;
        w2sum[r]     = acc0;
        w2sum[r + 1] = acc1;
    }
}

// --------------------------------------------------------------------------
// Kernel B: vT[d*E + e] = dot(w1[e,d,:], w2sum[e,:]).
// 2048 blocks x 256 thr. Block = expert e = bid>>8, rows d0 = (bid&255)*4.
// Stages 4 w1 rows (32 KB) + w2sum[e] (8 KB) via global_load_lds (10
// independent issues/thread), then wave w dots local row w against ws.
// c[e] computed by wave 0 of each expert's first block (float4-vectorized).
// --------------------------------------------------------------------------
__global__ __launch_bounds__(256) void v_build_kernel(const float* __restrict__ w1,
                                                      const float* __restrict__ w2sum,
                                                      const float* __restrict__ b1,
                                                      const float* __restrict__ b2,
                                                      float* __restrict__ vT,
                                                      float* __restrict__ c) {
    __shared__ float smw1[4 * H_];                     // 32 KB
    __shared__ float smws[H_];                         //  8 KB
    int bid  = blockIdx.x;
    int e    = bid >> 8;                               // 256 blocks/expert
    int d0   = (bid & 255) * 4;
    int wid  = threadIdx.x >> 6;
    int lane = threadIdx.x & 63;

    const float* w1src = w1 + ((size_t)e * D_ + d0) * H_;
    const float* wssrc = w2sum + (size_t)e * H_;
#pragma unroll
    for (int i = 0; i < 8; ++i) {
        int base = i * 1024 + wid * 256;
        stage16(w1src + base + lane * 4, smw1 + base);
    }
#pragma unroll
    for (int i = 0; i < 2; ++i) {
        int base = i * 1024 + wid * 256;
        stage16(wssrc + base + lane * 4, smws + base);
    }
    asm volatile("s_waitcnt vmcnt(0)" ::: "memory");
    __syncthreads();

    // wave w: local row w (2048 floats)
    const float* row = smw1 + wid * H_;
    float acc = 0.f;
#pragma unroll
    for (int k = 0; k < 8; ++k) {
        float4 a = *(const float4*)&row[lane * 4 + k * 256];
        float4 s = *(const float4*)&smws[lane * 4 + k * 256];
        acc += a.x * s.x + a.y * s.y + a.z * s.z + a.w * s.w;
    }
#pragma unroll
    for (int off = 32; off >= 1; off >>= 1) acc += __shfl_xor(acc, off, 64);
    if (lane == 0) {
        int d = d0 + wid;
        vT[(size_t)d * E_ + e] = acc;
    }

    // c[e] = dot(b1[e,:], w2sum[e,:]) + sum_d b2[e,d]  (vectorized)
    if ((bid & 255) == 0 && wid == 0) {
        float s = 0.f;
#pragma unroll
        for (int k = 0; k < 8; ++k) {
            float4 bb = *(const float4*)&b1[(size_t)e * H_ + lane * 4 + k * 256];
            float4 ww = *(const float4*)&smws[lane * 4 + k * 256];
            s += bb.x * ww.x + bb.y * ww.y + bb.z * ww.z + bb.w * ww.w;
        }
#pragma unroll
        for (int k = 0; k < 4; ++k) {
            float4 bb = *(const float4*)&b2[(size_t)e * D_ + lane * 4 + k * 256];
            s += bb.x + bb.y + bb.z + bb.w;
        }
#pragma unroll
        for (int off = 32; off >= 1; off >>= 1) s += __shfl_xor(s, off, 64);
        if (lane == 0) c[e] = s;
    }
}

// --------------------------------------------------------------------------
// Kernel C: per-token gating + collapsed expert sum. 2 tokens per wave.
//   logits[e] = x[n,:].wg[:,e] ; dv[e] = x[n,:].vT[:,e]
//   top-2 (tie -> lower index); g1 = 1/(1+exp(l0-l1)); s[n] = sum g*(dv+c)
// 512 blocks x 256 thr = 2048 waves.
// --------------------------------------------------------------------------
__global__ __launch_bounds__(256) void token_kernel(const float* __restrict__ x,
                                                    const float* __restrict__ wg,
                                                    const float* __restrict__ vT,
                                                    const float* __restrict__ c,
                                                    float* __restrict__ s) {
    int w = (blockIdx.x * 256 + threadIdx.x) >> 6;      // 0..2047
    int lane = threadIdx.x & 63;
    int n0 = w * 2;
    const float* x0 = x + (size_t)n0 * D_;
    const float* x1 = x0 + D_;

    float lgA[E_] = {0.f,0.f,0.f,0.f,0.f,0.f,0.f,0.f};
    float dvA[E_] = {0.f,0.f,0.f,0.f,0.f,0.f,0.f,0.f};
    float lgB[E_] = {0.f,0.f,0.f,0.f,0.f,0.f,0.f,0.f};
    float dvB[E_] = {0.f,0.f,0.f,0.f,0.f,0.f,0.f,0.f};

#pragma unroll
    for (int k = 0; k < D_ / 64; ++k) {                 // 16 iters
        int d = lane + 64 * k;
        float xa = x0[d];
        float xb = x1[d];
        const float4* wgp = (const float4*)(wg + (size_t)d * E_);
        const float4* vp  = (const float4*)(vT + (size_t)d * E_);
        float4 g0 = wgp[0], g1 = wgp[1];
        float4 v0 = vp[0],  v1 = vp[1];
        lgA[0] += xa * g0.x; lgA[1] += xa * g0.y; lgA[2] += xa * g0.z; lgA[3] += xa * g0.w;
        lgA[4] += xa * g1.x; lgA[5] += xa * g1.y; lgA[6] += xa * g1.z; lgA[7] += xa * g1.w;
        dvA[0] += xa * v0.x; dvA[1] += xa * v0.y; dvA[2] += xa * v0.z; dvA[3] += xa * v0.w;
        dvA[4] += xa * v1.x; dvA[5] += xa * v1.y; dvA[6] += xa * v1.z; dvA[7] += xa * v1.w;
        lgB[0] += xb * g0.x; lgB[1] += xb * g0.y; lgB[2] += xb * g0.z; lgB[3] += xb * g0.w;
        lgB[4] += xb * g1.x; lgB[5] += xb * g1.y; lgB[6] += xb * g1.z; lgB[7] += xb * g1.w;
        dvB[0] += xb * v0.x; dvB[1] += xb * v0.y; dvB[2] += xb * v0.z; dvB[3] += xb * v0.w;
        dvB[4] += xb * v1.x; dvB[5] += xb * v1.y; dvB[6] += xb * v1.z; dvB[7] += xb * v1.w;
    }

#pragma unroll
    for (int off = 32; off >= 1; off >>= 1) {
#pragma unroll
        for (int e = 0; e < E_; ++e) {
            lgA[e] += __shfl_xor(lgA[e], off, 64);
            dvA[e] += __shfl_xor(dvA[e], off, 64);
            lgB[e] += __shfl_xor(lgB[e], off, 64);
            dvB[e] += __shfl_xor(dvB[e], off, 64);
        }
    }

    if (lane == 0 || lane == 32) {
        const float* lg = (lane == 0) ? lgA : lgB;
        const float* dv = (lane == 0) ? dvA : dvB;
        int n = (lane == 0) ? n0 : (n0 + 1);
        int e0 = 0;
#pragma unroll
        for (int e = 1; e < E_; ++e) if (lg[e] > lg[e0]) e0 = e;
        int e1 = (e0 == 0) ? 1 : 0;
#pragma unroll
        for (int e = 0; e < E_; ++e) {
            if (e == e0) continue;
            if (lg[e] > lg[e1]) e1 = e;
        }
        float l0 = lg[e0], l1 = lg[e1];
        float g1w = 1.f / (1.f + expf(l0 - l1));
        float g0w = 1.f - g1w;
        s[n] = g0w * (dv[e0] + c[e0]) + g1w * (dv[e1] + c[e1]);
    }
}

// --------------------------------------------------------------------------
// Kernel D: out[b, t] = s[b, t] - logsumexp_t(s[b, :]).
// One block, 4 waves, wave per batch row; 16 values per lane.
// --------------------------------------------------------------------------
__global__ __launch_bounds__(256) void lsm_kernel(const float* __restrict__ s,
                                                  float* __restrict__ out) {
    int brow = threadIdx.x >> 6;                        // 0..3
    int lane = threadIdx.x & 63;
    const float* row = s + (size_t)brow * T_;
    float vals[16];
    float mx = -3.0e38f;
#pragma unroll
    for (int k = 0; k < 16; ++k) {
        vals[k] = row[lane + 64 * k];
        mx = fmaxf(mx, vals[k]);
    }
#pragma unroll
    for (int off = 32; off >= 1; off >>= 1) mx = fmaxf(mx, __shfl_xor(mx, off, 64));
    float sm = 0.f;
#pragma unroll
    for (int k = 0; k < 16; ++k) sm += expf(vals[k] - mx);
#pragma unroll
    for (int off = 32; off >= 1; off >>= 1) sm += __shfl_xor(sm, off, 64);
    float lse = mx + logf(sm);
#pragma unroll
    for (int k = 0; k < 16; ++k) out[(size_t)brow * T_ + lane + 64 * k] = vals[k] - lse;
}

// --------------------------------------------------------------------------
extern "C" void kernel_launch(void* const* d_in, const int* in_sizes, int n_in,
                              void* d_out, int out_size, void* d_ws, size_t ws_size,
                              hipStream_t stream) {
    const float* x  = (const float*)d_in[0];   // [B, T, D]
    const float* wg = (const float*)d_in[1];   // [D, E]
    const float* w1 = (const float*)d_in[2];   // [E, D, H]
    const float* b1 = (const float*)d_in[3];   // [E, H]
    const float* w2 = (const float*)d_in[4];   // [E, H, D]
    const float* b2 = (const float*)d_in[5];   // [E, D]
    float* out = (float*)d_out;                // [B, T]

    float* ws     = (float*)d_ws;
    float* w2sum  = ws;                 // E*H = 16384 floats
    float* vT     = ws + 16384;         // D*E =  8192 floats (transposed: [D][E])
    float* c      = ws + 24576;         // E   =     8 floats
    float* s      = ws + 24592;         // N   =  4096 floats

    // A: 16384 rows, 8 rows/block -> 2048 blocks (global_load_lds staging)
    w2sum_kernel<<<dim3(2048), dim3(256), 0, stream>>>(w2, w2sum);
    // B: 8192 rows, 4 rows/block -> 2048 blocks (global_load_lds staging)
    v_build_kernel<<<dim3(2048), dim3(256), 0, stream>>>(w1, w2sum, b1, b2, vT, c);
    // C: 4096 tokens, 2/wave -> 2048 waves -> 512 blocks
    token_kernel<<<dim3(512), dim3(256), 0, stream>>>(x, wg, vT, c, s);
    // D: log-softmax over T per batch row, single block
    lsm_kernel<<<dim3(1), dim3(256), 0, stream>>>(s, out);
}

// Round 7
// 47.001 us; speedup vs baseline: 1.3720x; 1.0544x over previous
//
#include <hip/hip_runtime.h>
#include <stdint.h>

// Problem constants
#define B_ 4
#define T_ 1024
#define D_ 1024
#define H_ 2048
#define E_ 8
#define N_ (B_ * T_)

// Fire-and-forget global->LDS staging, 16B per lane per issue.
// LDS dest: wave-uniform base (HW adds lane*16). Global src: per-lane.
__device__ __forceinline__ void stage16(const float* g, float* l) {
    __builtin_amdgcn_global_load_lds(
        (const __attribute__((address_space(1))) uint32_t*)g,
        (__attribute__((address_space(3))) uint32_t*)l,
        16, 0, 0);
}

// --------------------------------------------------------------------------
// Kernel A: w2sum[r] = sum_d w2_flat[r, d], row = D = 1024 contiguous floats.
// 1024 blocks x 256 thr; block owns 16 rows as TWO double-buffered 8-row
// tiles. All 16 staging issues go out first; counted vmcnt(8) lets tile-1's
// loads stay in flight while tile-0 is reduced (T3/T4 pattern).
// --------------------------------------------------------------------------
__global__ __launch_bounds__(256) void w2sum_kernel(const float* __restrict__ w2,
                                                    float* __restrict__ w2sum) {
    __shared__ float buf0[8 * D_];                     // 32 KB
    __shared__ float buf1[8 * D_];                     // 32 KB
    int wid  = threadIdx.x >> 6;
    int lane = threadIdx.x & 63;
    const float* src = w2 + (size_t)blockIdx.x * 16 * D_;

#pragma unroll
    for (int i = 0; i < 8; ++i) {                      // tile 0
        int base = i * 1024 + wid * 256;
        stage16(src + base + lane * 4, buf0 + base);
    }
#pragma unroll
    for (int i = 0; i < 8; ++i) {                      // tile 1
        int base = i * 1024 + wid * 256;
        stage16(src + 8192 + base + lane * 4, buf1 + base);
    }

    asm volatile("s_waitcnt vmcnt(8)" ::: "memory");   // own tile-0 issues done
    __builtin_amdgcn_s_barrier();                      // all waves' tile-0 done

    // compute tile 0: wave w reduces rows 2w, 2w+1
    {
        float acc0 = 0.f, acc1 = 0.f;
        const float* r0 = buf0 + (wid * 2) * D_;
        const float* r1 = r0 + D_;
#pragma unroll
        for (int k = 0; k < 4; ++k) {
            float4 a = *(const float4*)&r0[lane * 4 + k * 256];
            float4 b = *(const float4*)&r1[lane * 4 + k * 256];
            acc0 += a.x + a.y + a.z + a.w;
            acc1 += b.x + b.y + b.z + b.w;
        }
#pragma unroll
        for (int off = 32; off >= 1; off >>= 1) {
            acc0 += __shfl_xor(acc0, off, 64);
            acc1 += __shfl_xor(acc1, off, 64);
        }
        if (lane == 0) {
            int r = blockIdx.x * 16 + wid * 2;
            w2sum[r]     = acc0;
            w2sum[r + 1] = acc1;
        }
    }

    asm volatile("s_waitcnt vmcnt(0)" ::: "memory");
    __builtin_amdgcn_s_barrier();

    // compute tile 1
    {
        float acc0 = 0.f, acc1 = 0.f;
        const float* r0 = buf1 + (wid * 2) * D_;
        const float* r1 = r0 + D_;
#pragma unroll
        for (int k = 0; k < 4; ++k) {
            float4 a = *(const float4*)&r0[lane * 4 + k * 256];
            float4 b = *(const float4*)&r1[lane * 4 + k * 256];
            acc0 += a.x + a.y + a.z + a.w;
            acc1 += b.x + b.y + b.z + b.w;
        }
#pragma unroll
        for (int off = 32; off >= 1; off >>= 1) {
            acc0 += __shfl_xor(acc0, off, 64);
            acc1 += __shfl_xor(acc1, off, 64);
        }
        if (lane == 0) {
            int r = blockIdx.x * 16 + 8 + wid * 2;
            w2sum[r]     = acc0;
            w2sum[r + 1] = acc1;
        }
    }
}

// --------------------------------------------------------------------------
// Kernel B: vT[d*E + e] = dot(w1[e,d,:], w2sum[e,:]).
// 1024 blocks x 256 thr. Block = expert e = bid>>7, rows d0 = (bid&127)*8,
// as TWO double-buffered 4-row tiles (wave = 1 row). Stage order:
// w2sum (2 issues) + tile0 (8) + tile1 (8); vmcnt(8) => w2sum+tile0 landed,
// tile-1 still in flight during tile-0 compute. c[e] tail from LDS.
// --------------------------------------------------------------------------
__global__ __launch_bounds__(256) void v_build_kernel(const float* __restrict__ w1,
                                                      const float* __restrict__ w2sum,
                                                      const float* __restrict__ b1,
                                                      const float* __restrict__ b2,
                                                      float* __restrict__ vT,
                                                      float* __restrict__ c) {
    __shared__ float smw10[4 * H_];                    // 32 KB
    __shared__ float smw11[4 * H_];                    // 32 KB
    __shared__ float smws[H_];                         //  8 KB
    int bid  = blockIdx.x;
    int e    = bid >> 7;                               // 128 blocks/expert
    int d0   = (bid & 127) * 8;
    int wid  = threadIdx.x >> 6;
    int lane = threadIdx.x & 63;

    const float* w1src = w1 + ((size_t)e * D_ + d0) * H_;
    const float* wssrc = w2sum + (size_t)e * H_;

#pragma unroll
    for (int i = 0; i < 2; ++i) {                      // w2sum[e]
        int base = i * 1024 + wid * 256;
        stage16(wssrc + base + lane * 4, smws + base);
    }
#pragma unroll
    for (int i = 0; i < 8; ++i) {                      // tile 0: rows d0..d0+3
        int base = i * 1024 + wid * 256;
        stage16(w1src + base + lane * 4, smw10 + base);
    }
#pragma unroll
    for (int i = 0; i < 8; ++i) {                      // tile 1: rows d0+4..d0+7
        int base = i * 1024 + wid * 256;
        stage16(w1src + 8192 + base + lane * 4, smw11 + base);
    }

    asm volatile("s_waitcnt vmcnt(8)" ::: "memory");   // w2sum + tile0 done
    __builtin_amdgcn_s_barrier();

    // tile 0: wave w dots row w
    {
        const float* row = smw10 + wid * H_;
        float acc = 0.f;
#pragma unroll
        for (int k = 0; k < 8; ++k) {
            float4 a = *(const float4*)&row[lane * 4 + k * 256];
            float4 s = *(const float4*)&smws[lane * 4 + k * 256];
            acc += a.x * s.x + a.y * s.y + a.z * s.z + a.w * s.w;
        }
#pragma unroll
        for (int off = 32; off >= 1; off >>= 1) acc += __shfl_xor(acc, off, 64);
        if (lane == 0) vT[(size_t)(d0 + wid) * E_ + e] = acc;
    }

    asm volatile("s_waitcnt vmcnt(0)" ::: "memory");
    __builtin_amdgcn_s_barrier();

    // tile 1
    {
        const float* row = smw11 + wid * H_;
        float acc = 0.f;
#pragma unroll
        for (int k = 0; k < 8; ++k) {
            float4 a = *(const float4*)&row[lane * 4 + k * 256];
            float4 s = *(const float4*)&smws[lane * 4 + k * 256];
            acc += a.x * s.x + a.y * s.y + a.z * s.z + a.w * s.w;
        }
#pragma unroll
        for (int off = 32; off >= 1; off >>= 1) acc += __shfl_xor(acc, off, 64);
        if (lane == 0) vT[(size_t)(d0 + 4 + wid) * E_ + e] = acc;
    }

    // c[e] = dot(b1[e,:], w2sum[e,:]) + sum_d b2[e,d]
    if ((bid & 127) == 0 && wid == 0) {
        float s = 0.f;
#pragma unroll
        for (int k = 0; k < 8; ++k) {
            float4 bb = *(const float4*)&b1[(size_t)e * H_ + lane * 4 + k * 256];
            float4 ww = *(const float4*)&smws[lane * 4 + k * 256];
            s += bb.x * ww.x + bb.y * ww.y + bb.z * ww.z + bb.w * ww.w;
        }
#pragma unroll
        for (int k = 0; k < 4; ++k) {
            float4 bb = *(const float4*)&b2[(size_t)e * D_ + lane * 4 + k * 256];
            s += bb.x + bb.y + bb.z + bb.w;
        }
#pragma unroll
        for (int off = 32; off >= 1; off >>= 1) s += __shfl_xor(s, off, 64);
        if (lane == 0) c[e] = s;
    }
}

// --------------------------------------------------------------------------
// Kernel C: per-token gating + collapsed expert sum. ONE token per wave
// (16 waves/CU, low VGPR -> better latency hiding than 2-token version).
//   logits[e] = x[n,:].wg[:,e] ; dv[e] = x[n,:].vT[:,e]
//   top-2 (tie -> lower index); g1 = 1/(1+exp(l0-l1)); s[n] = sum g*(dv+c)
// 1024 blocks x 256 thr = 4096 waves.
// --------------------------------------------------------------------------
__global__ __launch_bounds__(256) void token_kernel(const float* __restrict__ x,
                                                    const float* __restrict__ wg,
                                                    const float* __restrict__ vT,
                                                    const float* __restrict__ c,
                                                    float* __restrict__ s) {
    int wid  = threadIdx.x >> 6;
    int lane = threadIdx.x & 63;
    int n = blockIdx.x * 4 + wid;
    const float* xr = x + (size_t)n * D_;

    float lg[E_] = {0.f,0.f,0.f,0.f,0.f,0.f,0.f,0.f};
    float dv[E_] = {0.f,0.f,0.f,0.f,0.f,0.f,0.f,0.f};

#pragma unroll
    for (int k = 0; k < D_ / 64; ++k) {                 // 16 iters
        int d = lane + 64 * k;
        float xv = xr[d];
        const float4* wgp = (const float4*)(wg + (size_t)d * E_);
        const float4* vp  = (const float4*)(vT + (size_t)d * E_);
        float4 g0 = wgp[0], g1 = wgp[1];
        float4 v0 = vp[0],  v1 = vp[1];
        lg[0] += xv * g0.x; lg[1] += xv * g0.y; lg[2] += xv * g0.z; lg[3] += xv * g0.w;
        lg[4] += xv * g1.x; lg[5] += xv * g1.y; lg[6] += xv * g1.z; lg[7] += xv * g1.w;
        dv[0] += xv * v0.x; dv[1] += xv * v0.y; dv[2] += xv * v0.z; dv[3] += xv * v0.w;
        dv[4] += xv * v1.x; dv[5] += xv * v1.y; dv[6] += xv * v1.z; dv[7] += xv * v1.w;
    }

#pragma unroll
    for (int off = 32; off >= 1; off >>= 1) {
#pragma unroll
        for (int e = 0; e < E_; ++e) {
            lg[e] += __shfl_xor(lg[e], off, 64);
            dv[e] += __shfl_xor(dv[e], off, 64);
        }
    }

    if (lane == 0) {
        int e0 = 0;
#pragma unroll
        for (int e = 1; e < E_; ++e) if (lg[e] > lg[e0]) e0 = e;
        int e1 = (e0 == 0) ? 1 : 0;
#pragma unroll
        for (int e = 0; e < E_; ++e) {
            if (e == e0) continue;
            if (lg[e] > lg[e1]) e1 = e;
        }
        float l0 = lg[e0], l1 = lg[e1];
        float g1w = 1.f / (1.f + expf(l0 - l1));
        float g0w = 1.f - g1w;
        s[n] = g0w * (dv[e0] + c[e0]) + g1w * (dv[e1] + c[e1]);
    }
}

// --------------------------------------------------------------------------
// Kernel D: out[b, t] = s[b, t] - logsumexp_t(s[b, :]).
// One block, 4 waves, wave per batch row; 16 values per lane.
// --------------------------------------------------------------------------
__global__ __launch_bounds__(256) void lsm_kernel(const float* __restrict__ s,
                                                  float* __restrict__ out) {
    int brow = threadIdx.x >> 6;                        // 0..3
    int lane = threadIdx.x & 63;
    const float* row = s + (size_t)brow * T_;
    float vals[16];
    float mx = -3.0e38f;
#pragma unroll
    for (int k = 0; k < 16; ++k) {
        vals[k] = row[lane + 64 * k];
        mx = fmaxf(mx, vals[k]);
    }
#pragma unroll
    for (int off = 32; off >= 1; off >>= 1) mx = fmaxf(mx, __shfl_xor(mx, off, 64));
    float sm = 0.f;
#pragma unroll
    for (int k = 0; k < 16; ++k) sm += expf(vals[k] - mx);
#pragma unroll
    for (int off = 32; off >= 1; off >>= 1) sm += __shfl_xor(sm, off, 64);
    float lse = mx + logf(sm);
#pragma unroll
    for (int k = 0; k < 16; ++k) out[(size_t)brow * T_ + lane + 64 * k] = vals[k] - lse;
}

// --------------------------------------------------------------------------
extern "C" void kernel_launch(void* const* d_in, const int* in_sizes, int n_in,
                              void* d_out, int out_size, void* d_ws, size_t ws_size,
                              hipStream_t stream) {
    const float* x  = (const float*)d_in[0];   // [B, T, D]
    const float* wg = (const float*)d_in[1];   // [D, E]
    const float* w1 = (const float*)d_in[2];   // [E, D, H]
    const float* b1 = (const float*)d_in[3];   // [E, H]
    const float* w2 = (const float*)d_in[4];   // [E, H, D]
    const float* b2 = (const float*)d_in[5];   // [E, D]
    float* out = (float*)d_out;                // [B, T]

    float* ws     = (float*)d_ws;
    float* w2sum  = ws;                 // E*H = 16384 floats
    float* vT     = ws + 16384;         // D*E =  8192 floats (transposed: [D][E])
    float* c      = ws + 24576;         // E   =     8 floats
    float* s      = ws + 24592;         // N   =  4096 floats

    // A: 16384 rows, 16 rows/block (2 pipelined tiles) -> 1024 blocks
    w2sum_kernel<<<dim3(1024), dim3(256), 0, stream>>>(w2, w2sum);
    // B: 8192 rows, 8 rows/block (2 pipelined tiles) -> 1024 blocks
    v_build_kernel<<<dim3(1024), dim3(256), 0, stream>>>(w1, w2sum, b1, b2, vT, c);
    // C: 4096 tokens, 1/wave -> 1024 blocks
    token_kernel<<<dim3(1024), dim3(256), 0, stream>>>(x, wg, vT, c, s);
    // D: log-softmax over T per batch row, single block
    lsm_kernel<<<dim3(1), dim3(256), 0, stream>>>(s, out);
}

// Round 8
// 45.124 us; speedup vs baseline: 1.4291x; 1.0416x over previous
//
#include <hip/hip_runtime.h>
#include <stdint.h>

// Problem constants
#define B_ 4
#define T_ 1024
#define D_ 1024
#define H_ 2048
#define E_ 8

// Fire-and-forget global->LDS staging, 16B per lane per issue.
// LDS dest: wave-uniform base (HW adds lane*16). Global src: per-lane.
__device__ __forceinline__ void stage16(const float* g, float* l) {
    __builtin_amdgcn_global_load_lds(
        (const __attribute__((address_space(1))) uint32_t*)g,
        (__attribute__((address_space(3))) uint32_t*)l, 16, 0, 0);
}

// --------------------------------------------------------------------------
// Kernel A: w2sum[r] = sum_d w2_flat[r, d] (row = D = 1024 floats).
// 512 blocks x 256 thr; block = 32 rows = 8 tiles of 4 rows, TRIPLE-buffered.
// Wave-private pipeline: wave wid stages AND reduces row wid of each tile
// (same 4 KB LDS slice) -> NO barriers. 2 tiles (8 KB/wave) always in
// flight; counted vmcnt(4); stores deferred to end (keeps vmcnt math exact).
// --------------------------------------------------------------------------
__global__ __launch_bounds__(256) void w2sum_kernel(const float* __restrict__ w2,
                                                    float* __restrict__ w2sum) {
    __shared__ float buf[3][4 * D_];                   // 48 KB
    const int wid = threadIdx.x >> 6, lane = threadIdx.x & 63;
    const float* src = w2 + (size_t)blockIdx.x * 32 * D_ + wid * D_ + lane * 4;

#define A_STAGE(k)                                                        \
    {                                                                     \
        const float* s_ = src + (k) * (4 * D_);                           \
        float* d_ = &buf[(k) % 3][wid * D_];                              \
        stage16(s_,       d_);       stage16(s_ + 256, d_ + 256);         \
        stage16(s_ + 512, d_ + 512); stage16(s_ + 768, d_ + 768);         \
    }

    A_STAGE(0); A_STAGE(1);
    float accs[8];
#pragma unroll
    for (int k = 0; k < 8; ++k) {
        if (k < 7) asm volatile("s_waitcnt vmcnt(4)" ::: "memory");  // tile k landed
        else       asm volatile("s_waitcnt vmcnt(0)" ::: "memory");
        if (k < 6) A_STAGE(k + 2);                     // issue-early, buffer free since k-1
        const float* row = &buf[k % 3][wid * D_];
        float acc = 0.f;
#pragma unroll
        for (int j = 0; j < 4; ++j) {
            float4 a = *(const float4*)&row[j * 256 + lane * 4];
            acc += a.x + a.y + a.z + a.w;
        }
#pragma unroll
        for (int off = 32; off >= 1; off >>= 1) acc += __shfl_xor(acc, off, 64);
        accs[k] = acc;
    }
    if (lane == 0) {
        int r0 = blockIdx.x * 32 + wid;
#pragma unroll
        for (int k = 0; k < 8; ++k) w2sum[r0 + k * 4] = accs[k];
    }
#undef A_STAGE
}

// --------------------------------------------------------------------------
// Kernel B: vT[d*E + e] = dot(w1[e,d,:], w2sum[e,:]).
// 512 blocks x 256 thr; block = expert bid>>6, rows d0=(bid&63)*16 as
// 4 tiles of 4 rows, DOUBLE-buffered (64 KB). w2sum[e] fragment lives in
// 8 float4 REGISTERS per wave (loaded once; no LDS reads for operand 2).
// Wave-private: wave wid stages & dots row wid of each tile; no barriers.
// Stage of tile k+2 placed AFTER tile-k reduce (same buffer; reads drained).
// c[e] computed from the ws registers by wave 0 of each expert's 1st block.
// --------------------------------------------------------------------------
__global__ __launch_bounds__(256) void v_build_kernel(const float* __restrict__ w1,
                                                      const float* __restrict__ w2sum,
                                                      const float* __restrict__ b1,
                                                      const float* __restrict__ b2,
                                                      float* __restrict__ vT,
                                                      float* __restrict__ c) {
    __shared__ float buf[2][4 * H_];                   // 64 KB
    const int bid = blockIdx.x;
    const int e   = bid >> 6;                          // 64 blocks/expert
    const int d0  = (bid & 63) * 16;
    const int wid = threadIdx.x >> 6, lane = threadIdx.x & 63;
    const float* src = w1 + ((size_t)e * D_ + d0 + wid) * H_ + lane * 4;

    // w2sum[e] fragment -> 8 float4 regs (issued before any staging; the
    // empty asm pins issue order so the vmcnt counts below stay exact).
    const float4* wsp = (const float4*)(w2sum + (size_t)e * H_) + lane;
    float4 s0 = wsp[0],   s1 = wsp[64],  s2 = wsp[128], s3 = wsp[192],
           s4 = wsp[256], s5 = wsp[320], s6 = wsp[384], s7 = wsp[448];
    asm volatile("" ::: "memory");

#define B_STAGE(k)                                                         \
    {                                                                      \
        const float* s_ = src + (size_t)(k) * 4 * H_;                      \
        float* d_ = &buf[(k) & 1][wid * H_];                               \
        stage16(s_,        d_);        stage16(s_ + 256,  d_ + 256);       \
        stage16(s_ + 512,  d_ + 512);  stage16(s_ + 768,  d_ + 768);       \
        stage16(s_ + 1024, d_ + 1024); stage16(s_ + 1280, d_ + 1280);      \
        stage16(s_ + 1536, d_ + 1536); stage16(s_ + 1792, d_ + 1792);      \
    }

    B_STAGE(0); B_STAGE(1);
    float accs[4];
#pragma unroll
    for (int k = 0; k < 4; ++k) {
        // iter0: outstanding = ws(8)+t0(8)+t1(8)=24 -> vmcnt(8) drains ws+t0.
        // steady: [tk(8), tk+1(8)] -> vmcnt(8) drains tk. last: vmcnt(0).
        if (k < 3) asm volatile("s_waitcnt vmcnt(8)" ::: "memory");
        else       asm volatile("s_waitcnt vmcnt(0)" ::: "memory");
        const float* row = &buf[k & 1][wid * H_];
        float acc;
        {
            float4 a0 = *(const float4*)&row[0 * 256 + lane * 4];
            float4 a1 = *(const float4*)&row[1 * 256 + lane * 4];
            float4 a2 = *(const float4*)&row[2 * 256 + lane * 4];
            float4 a3 = *(const float4*)&row[3 * 256 + lane * 4];
            float4 a4 = *(const float4*)&row[4 * 256 + lane * 4];
            float4 a5 = *(const float4*)&row[5 * 256 + lane * 4];
            float4 a6 = *(const float4*)&row[6 * 256 + lane * 4];
            float4 a7 = *(const float4*)&row[7 * 256 + lane * 4];
            acc = a0.x*s0.x + a0.y*s0.y + a0.z*s0.z + a0.w*s0.w
                + a1.x*s1.x + a1.y*s1.y + a1.z*s1.z + a1.w*s1.w
                + a2.x*s2.x + a2.y*s2.y + a2.z*s2.z + a2.w*s2.w
                + a3.x*s3.x + a3.y*s3.y + a3.z*s3.z + a3.w*s3.w
                + a4.x*s4.x + a4.y*s4.y + a4.z*s4.z + a4.w*s4.w
                + a5.x*s5.x + a5.y*s5.y + a5.z*s5.z + a5.w*s5.w
                + a6.x*s6.x + a6.y*s6.y + a6.z*s6.z + a6.w*s6.w
                + a7.x*s7.x + a7.y*s7.y + a7.z*s7.z + a7.w*s7.w;
        }
#pragma unroll
        for (int off = 32; off >= 1; off >>= 1) acc += __shfl_xor(acc, off, 64);
        accs[k] = acc;
        // reduce done => this buffer's LDS reads are drained; safe to overwrite
        if (k < 2) B_STAGE(k + 2);
    }
    if (lane == 0) {
#pragma unroll
        for (int k = 0; k < 4; ++k)
            vT[(size_t)(d0 + k * 4 + wid) * E_ + e] = accs[k];
    }

    // c[e] = dot(b1[e,:], w2sum[e,:]) + sum_d b2[e,d]   (ws regs still live)
    if ((bid & 63) == 0 && wid == 0) {
        const float4* bp = (const float4*)(b1 + (size_t)e * H_) + lane;
        float4 q0 = bp[0],   q1 = bp[64],  q2 = bp[128], q3 = bp[192],
               q4 = bp[256], q5 = bp[320], q6 = bp[384], q7 = bp[448];
        float s = q0.x*s0.x + q0.y*s0.y + q0.z*s0.z + q0.w*s0.w
                + q1.x*s1.x + q1.y*s1.y + q1.z*s1.z + q1.w*s1.w
                + q2.x*s2.x + q2.y*s2.y + q2.z*s2.z + q2.w*s2.w
                + q3.x*s3.x + q3.y*s3.y + q3.z*s3.z + q3.w*s3.w
                + q4.x*s4.x + q4.y*s4.y + q4.z*s4.z + q4.w*s4.w
                + q5.x*s5.x + q5.y*s5.y + q5.z*s5.z + q5.w*s5.w
                + q6.x*s6.x + q6.y*s6.y + q6.z*s6.z + q6.w*s6.w
                + q7.x*s7.x + q7.y*s7.y + q7.z*s7.z + q7.w*s7.w;
        const float4* cp = (const float4*)(b2 + (size_t)e * D_) + lane;
#pragma unroll
        for (int j = 0; j < 4; ++j) {
            float4 bb = cp[j * 64];
            s += bb.x + bb.y + bb.z + bb.w;
        }
#pragma unroll
        for (int off = 32; off >= 1; off >>= 1) s += __shfl_xor(s, off, 64);
        if (lane == 0) c[e] = s;
    }
#undef B_STAGE
}

// --------------------------------------------------------------------------
// Kernel C: per-token gating + collapsed expert sum. One token per wave.
//   logits[e] = x[n,:].wg[:,e] ; dv[e] = x[n,:].vT[:,e]
//   top-2 (tie -> lower index); g1 = 1/(1+exp(l0-l1)); s[n] = sum g*(dv+c)
// 1024 blocks x 256 thr = 4096 waves.
// --------------------------------------------------------------------------
__global__ __launch_bounds__(256) void token_kernel(const float* __restrict__ x,
                                                    const float* __restrict__ wg,
                                                    const float* __restrict__ vT,
                                                    const float* __restrict__ c,
                                                    float* __restrict__ s) {
    int wid  = threadIdx.x >> 6;
    int lane = threadIdx.x & 63;
    int n = blockIdx.x * 4 + wid;
    const float* xr = x + (size_t)n * D_;

    float lg[E_] = {0.f,0.f,0.f,0.f,0.f,0.f,0.f,0.f};
    float dv[E_] = {0.f,0.f,0.f,0.f,0.f,0.f,0.f,0.f};

#pragma unroll
    for (int k = 0; k < D_ / 64; ++k) {                 // 16 iters
        int d = lane + 64 * k;
        float xv = xr[d];
        const float4* wgp = (const float4*)(wg + (size_t)d * E_);
        const float4* vp  = (const float4*)(vT + (size_t)d * E_);
        float4 g0 = wgp[0], g1 = wgp[1];
        float4 v0 = vp[0],  v1 = vp[1];
        lg[0] += xv * g0.x; lg[1] += xv * g0.y; lg[2] += xv * g0.z; lg[3] += xv * g0.w;
        lg[4] += xv * g1.x; lg[5] += xv * g1.y; lg[6] += xv * g1.z; lg[7] += xv * g1.w;
        dv[0] += xv * v0.x; dv[1] += xv * v0.y; dv[2] += xv * v0.z; dv[3] += xv * v0.w;
        dv[4] += xv * v1.x; dv[5] += xv * v1.y; dv[6] += xv * v1.z; dv[7] += xv * v1.w;
    }

#pragma unroll
    for (int off = 32; off >= 1; off >>= 1) {
#pragma unroll
        for (int e = 0; e < E_; ++e) {
            lg[e] += __shfl_xor(lg[e], off, 64);
            dv[e] += __shfl_xor(dv[e], off, 64);
        }
    }

    if (lane == 0) {
        int e0 = 0;
#pragma unroll
        for (int e = 1; e < E_; ++e) if (lg[e] > lg[e0]) e0 = e;
        int e1 = (e0 == 0) ? 1 : 0;
#pragma unroll
        for (int e = 0; e < E_; ++e) {
            if (e == e0) continue;
            if (lg[e] > lg[e1]) e1 = e;
        }
        float l0 = lg[e0], l1 = lg[e1];
        float g1w = 1.f / (1.f + expf(l0 - l1));
        float g0w = 1.f - g1w;
        s[n] = g0w * (dv[e0] + c[e0]) + g1w * (dv[e1] + c[e1]);
    }
}

// --------------------------------------------------------------------------
// Kernel D: out[b, t] = s[b, t] - logsumexp_t(s[b, :]).
// 4 blocks x 64 thr; one wave per batch row; 16 values per lane.
// --------------------------------------------------------------------------
__global__ __launch_bounds__(64) void lsm_kernel(const float* __restrict__ s,
                                                 float* __restrict__ out) {
    int brow = blockIdx.x;
    int lane = threadIdx.x & 63;
    const float* row = s + (size_t)brow * T_;
    float vals[16];
    float mx = -3.0e38f;
#pragma unroll
    for (int k = 0; k < 16; ++k) {
        vals[k] = row[lane + 64 * k];
        mx = fmaxf(mx, vals[k]);
    }
#pragma unroll
    for (int off = 32; off >= 1; off >>= 1) mx = fmaxf(mx, __shfl_xor(mx, off, 64));
    float sm = 0.f;
#pragma unroll
    for (int k = 0; k < 16; ++k) sm += expf(vals[k] - mx);
#pragma unroll
    for (int off = 32; off >= 1; off >>= 1) sm += __shfl_xor(sm, off, 64);
    float lse = mx + logf(sm);
#pragma unroll
    for (int k = 0; k < 16; ++k) out[(size_t)brow * T_ + lane + 64 * k] = vals[k] - lse;
}

// --------------------------------------------------------------------------
extern "C" void kernel_launch(void* const* d_in, const int* in_sizes, int n_in,
                              void* d_out, int out_size, void* d_ws, size_t ws_size,
                              hipStream_t stream) {
    const float* x  = (const float*)d_in[0];   // [B, T, D]
    const float* wg = (const float*)d_in[1];   // [D, E]
    const float* w1 = (const float*)d_in[2];   // [E, D, H]
    const float* b1 = (const float*)d_in[3];   // [E, H]
    const float* w2 = (const float*)d_in[4];   // [E, H, D]
    const float* b2 = (const float*)d_in[5];   // [E, D]
    float* out = (float*)d_out;                // [B, T]

    float* ws     = (float*)d_ws;
    float* w2sum  = ws;                 // E*H = 16384 floats
    float* vT     = ws + 16384;         // D*E =  8192 floats (transposed: [D][E])
    float* c      = ws + 24576;         // E   =     8 floats
    float* s      = ws + 24592;         // N   =  4096 floats

    // A: 16384 rows, 32 rows/block (8-tile rolling pipeline) -> 512 blocks
    w2sum_kernel<<<dim3(512), dim3(256), 0, stream>>>(w2, w2sum);
    // B: 8192 rows, 16 rows/block (4-tile rolling pipeline) -> 512 blocks
    v_build_kernel<<<dim3(512), dim3(256), 0, stream>>>(w1, w2sum, b1, b2, vT, c);
    // C: 4096 tokens, 1/wave -> 1024 blocks
    token_kernel<<<dim3(1024), dim3(256), 0, stream>>>(x, wg, vT, c, s);
    // D: log-softmax over T per batch row, 4 blocks
    lsm_kernel<<<dim3(4), dim3(64), 0, stream>>>(s, out);
}